// Round 5
// baseline (377.463 us; speedup 1.0000x reference)
//
#include <hip/hip_runtime.h>

#define NCLS 21
#define HW (512 * 512)
#define NP (HW / 2)          // 131072 pixel-pairs per image
#define BATCH 8
#define BLOCK 256
#define GRIDX (NP / BLOCK)   // 512 blocks per image
#define REPS 8               // diagnostic amplification; ws accumulates 8x both
                             // i and u -> ratio i/u unchanged (u >> 1 always)

// ws layout (floats): [0..167] union[b][c], [168..335] intersect[b][c]
#define WS_FLOATS (2 * BATCH * NCLS)

__global__ void zero_ws_kernel(float* ws) {
    int i = blockIdx.x * blockDim.x + threadIdx.x;
    if (i < WS_FLOATS) ws[i] = 0.0f;
}

__global__ __launch_bounds__(BLOCK) void iou_partial_kernel(
        const float* __restrict__ in,   // [B, C, H, W]
        const int* __restrict__ tgt,    // [B, H, W]
        float* __restrict__ ws) {
    const int b = blockIdx.y;
    const float2* __restrict__ in2 = (const float2*)(in + (size_t)b * NCLS * HW);
    const int2*   __restrict__ tb2 = (const int2*)(tgt + (size_t)b * HW);

    __shared__ float s_u[NCLS];
    __shared__ float s_i[NCLS];
    if (threadIdx.x < NCLS) { s_u[threadIdx.x] = 0.0f; s_i[threadIdx.x] = 0.0f; }
    __syncthreads();

    const int p0 = blockIdx.x * BLOCK + threadIdx.x;   // pair index

    for (int rep = 0; rep < REPS; ++rep) {
        // rotate pixel assignment per rep: bijection on [0, NP) -> each rep
        // covers the full image exactly once (8x accumulation, no L1/L2 reuse
        // within a block so warm reps exercise L3, not L1)
        const int p = (p0 + rep * (NP / REPS)) & (NP - 1);

        const int2 t2 = tb2[p];
        float2 x[NCLS];
        #pragma unroll
        for (int c = 0; c < NCLS; ++c)
            x[c] = in2[(size_t)c * NP + p];

        const int t[2] = {t2.x, t2.y};
        #pragma unroll
        for (int j = 0; j < 2; ++j) {
            float v0 = (j == 0) ? x[0].x : x[0].y;
            float m  = v0;
            int   aj = 0;
            float vt = v0;
            #pragma unroll
            for (int c = 1; c < NCLS; ++c) {
                const float v = (j == 0) ? x[c].x : x[c].y;
                aj = (v > m) ? c : aj;     // strict >, first index on tie
                m  = fmaxf(m, v);
                vt = (c == t[j]) ? v : vt;
            }
            float s = 0.0f;
            #pragma unroll
            for (int c = 0; c < NCLS; ++c) {
                const float v = (j == 0) ? x[c].x : x[c].y;
                s += __expf(v - m);
            }
            const float p_pred = 1.0f / s;               // exp(m-m)/s
            const float p_t    = __expf(vt - m) * p_pred;
            const int   tj = t[j];
            const bool  eq = (tj == aj);
            // union 2->1 clamp: if eq, one union add + one intersect add;
            // else two union adds. Exactly 2 LDS atomics/pixel, branchless.
            atomicAdd(&s_u[aj], p_pred);
            atomicAdd(eq ? &s_i[aj] : &s_u[tj], eq ? p_pred : p_t);
        }
    }

    __syncthreads();
    if (threadIdx.x < NCLS) {
        atomicAdd(&ws[b * NCLS + threadIdx.x], s_u[threadIdx.x]);
        atomicAdd(&ws[BATCH * NCLS + b * NCLS + threadIdx.x], s_i[threadIdx.x]);
    }
}

__global__ __launch_bounds__(BLOCK) void finalize_kernel(
        const float* __restrict__ ws, float* __restrict__ out) {
    __shared__ float red[BLOCK];
    const int i = threadIdx.x;
    float val = 0.0f;
    if (i < BATCH * NCLS) {
        const float u  = ws[i];
        const float it = ws[BATCH * NCLS + i];
        const float ratio = it / fmaxf(u, 1.0f);
        const float d = ratio - 1.0f;
        val = d * d;
    }
    red[i] = val;
    __syncthreads();
    for (int off = BLOCK / 2; off > 0; off >>= 1) {
        if (i < off) red[i] += red[i + off];
        __syncthreads();
    }
    if (i == 0) out[0] = red[0] / (float)BATCH;
}

extern "C" void kernel_launch(void* const* d_in, const int* in_sizes, int n_in,
                              void* d_out, int out_size, void* d_ws, size_t ws_size,
                              hipStream_t stream) {
    const float* in  = (const float*)d_in[0];
    const int*   tgt = (const int*)d_in[1];
    float* ws  = (float*)d_ws;
    float* out = (float*)d_out;

    zero_ws_kernel<<<1, 512, 0, stream>>>(ws);
    dim3 grid(GRIDX, BATCH);
    iou_partial_kernel<<<grid, BLOCK, 0, stream>>>(in, tgt, ws);
    finalize_kernel<<<1, BLOCK, 0, stream>>>(ws, out);
}

// Round 6
// 248.026 us; speedup vs baseline: 1.5219x; 1.5219x over previous
//
#include <hip/hip_runtime.h>

#define NCLS 21
#define HW (512 * 512)
#define NP (HW / 2)          // 131072 pixel-pairs per image
#define BATCH 8
#define BLOCK 256
#define GRIDX (NP / BLOCK)   // 512 blocks per image

// ws layout (floats): [0..167] union[b][c], [168..335] intersect[b][c]
#define WS_FLOATS (2 * BATCH * NCLS)

__global__ void zero_ws_kernel(float* ws) {
    int i = blockIdx.x * blockDim.x + threadIdx.x;
    if (i < WS_FLOATS) ws[i] = 0.0f;
}

__global__ __launch_bounds__(BLOCK) void iou_partial_kernel(
        const float* __restrict__ in,   // [B, C, H, W]
        const int* __restrict__ tgt,    // [B, H, W]
        float* __restrict__ ws) {
    const int b = blockIdx.y;
    const float2* __restrict__ in2 = (const float2*)(in + (size_t)b * NCLS * HW);
    const int2*   __restrict__ tb2 = (const int2*)(tgt + (size_t)b * HW);

    __shared__ float s_u[NCLS];
    __shared__ float s_i[NCLS];
    if (threadIdx.x < NCLS) { s_u[threadIdx.x] = 0.0f; s_i[threadIdx.x] = 0.0f; }
    __syncthreads();

    const int p = blockIdx.x * BLOCK + threadIdx.x;   // pair index

    const int2 t2 = tb2[p];
    float2 x[NCLS];
    #pragma unroll
    for (int c = 0; c < NCLS; ++c)
        x[c] = in2[(size_t)c * NP + p];

    const int t[2] = {t2.x, t2.y};
    #pragma unroll
    for (int j = 0; j < 2; ++j) {
        const int tj = t[j];
        // pass 1: max + argmax (strict >, first index on tie)
        float m  = (j == 0) ? x[0].x : x[0].y;
        int   aj = 0;
        #pragma unroll
        for (int c = 1; c < NCLS; ++c) {
            const float v = (j == 0) ? x[c].x : x[c].y;
            const bool g = v > m;
            aj = g ? c : aj;
            m  = g ? v : m;
        }
        // pass 2: sum of exp + select e_target in the same sweep
        float s  = 0.0f;
        float et = 0.0f;
        #pragma unroll
        for (int c = 0; c < NCLS; ++c) {
            const float v = (j == 0) ? x[c].x : x[c].y;
            const float e = __expf(v - m);
            s += e;
            et = (c == tj) ? e : et;
        }
        const float p_pred = 1.0f / s;        // exp(m-m)/s
        const float p_t    = et * p_pred;
        const bool  eq = (tj == aj);
        // union 2->1 clamp: if eq, one union add + one intersect add;
        // else two union adds. Exactly 2 LDS atomics/pixel, branchless.
        atomicAdd(&s_u[aj], p_pred);
        atomicAdd(eq ? &s_i[aj] : &s_u[tj], eq ? p_pred : p_t);
    }

    __syncthreads();
    if (threadIdx.x < NCLS) {
        atomicAdd(&ws[b * NCLS + threadIdx.x], s_u[threadIdx.x]);
        atomicAdd(&ws[BATCH * NCLS + b * NCLS + threadIdx.x], s_i[threadIdx.x]);
    }
}

__global__ __launch_bounds__(BLOCK) void finalize_kernel(
        const float* __restrict__ ws, float* __restrict__ out) {
    __shared__ float red[BLOCK];
    const int i = threadIdx.x;
    float val = 0.0f;
    if (i < BATCH * NCLS) {
        const float u  = ws[i];
        const float it = ws[BATCH * NCLS + i];
        const float ratio = it / fmaxf(u, 1.0f);
        const float d = ratio - 1.0f;
        val = d * d;
    }
    red[i] = val;
    __syncthreads();
    for (int off = BLOCK / 2; off > 0; off >>= 1) {
        if (i < off) red[i] += red[i + off];
        __syncthreads();
    }
    if (i == 0) out[0] = red[0] / (float)BATCH;
}

extern "C" void kernel_launch(void* const* d_in, const int* in_sizes, int n_in,
                              void* d_out, int out_size, void* d_ws, size_t ws_size,
                              hipStream_t stream) {
    const float* in  = (const float*)d_in[0];
    const int*   tgt = (const int*)d_in[1];
    float* ws  = (float*)d_ws;
    float* out = (float*)d_out;

    zero_ws_kernel<<<1, 512, 0, stream>>>(ws);
    dim3 grid(GRIDX, BATCH);
    iou_partial_kernel<<<grid, BLOCK, 0, stream>>>(in, tgt, ws);
    finalize_kernel<<<1, BLOCK, 0, stream>>>(ws, out);
}